// Round 14
// baseline (126.900 us; speedup 1.0000x reference)
//
#include <hip/hip_runtime.h>
#include <cstdint>
#include <cstddef>

// ---------- constants for this problem ----------
#define BATCH 2
#define SEQ   2048
#define HID   1024
#define NHEAD 16
#define DHEAD 64
#define QKV_N 3072   // 3*HID
#define NTOK  4096   // BATCH*SEQ

typedef __attribute__((ext_vector_type(4))) float f32x4;
typedef __attribute__((ext_vector_type(8))) short bf16x8;

#define QSCL 0.18033688011112042f   // (1/8) * log2(e), folded into Q at GEMM epilogue

__device__ inline unsigned short f2bf(float f) {
    union { float f; unsigned int u; } v; v.f = f;
    unsigned int u = v.u;
    unsigned int r = (u + 0x7fffu + ((u >> 16) & 1u)) >> 16;
    return (unsigned short)r;
}

// pack two positive floats to bf16 pair (round-half-up): P in [0,1], no NaN/inf.
__device__ __forceinline__ unsigned int pack_bf16_rh(float a, float b) {
    union { float f; unsigned int u; } ua, ub;
    ua.f = a; ub.f = b;
    return ((ua.u + 0x8000u) >> 16) | ((ub.u + 0x8000u) & 0xffff0000u);
}

__device__ __forceinline__ void gload_lds16(const void* g, void* l) {
    __builtin_amdgcn_global_load_lds(
        (const __attribute__((address_space(1))) void*)g,
        (__attribute__((address_space(3))) void*)l, 16, 0, 0);
}

// ---------- cast fp32 -> bf16 (packed ushort4) ----------
__global__ void cast_f32_bf16(const float* __restrict__ in, unsigned short* __restrict__ out, int n4) {
    int i = blockIdx.x * blockDim.x + threadIdx.x;
    if (i >= n4) return;
    float4 v = reinterpret_cast<const float4*>(in)[i];
    ushort4 o;
    o.x = f2bf(v.x); o.y = f2bf(v.y); o.z = f2bf(v.z); o.w = f2bf(v.w);
    reinterpret_cast<ushort4*>(out)[i] = o;
}

// ---------- GEMM, 2-phase dbuf pipeline: C[M][N] = A[M][K] @ B[N][K]^T + bias ----------
// (unchanged from R5/R8 -- verified win)
template<int BN, int OUT_MODE>
__global__ __launch_bounds__(256) void gemm_bt(const short* __restrict__ A,
                                               const short* __restrict__ B,
                                               const float* __restrict__ bias,
                                               void* __restrict__ Cout,
                                               int M, int N, int K) {
    constexpr int WTN = BN / 2;
    constexpr int NJ  = WTN / 16;
    constexpr int NBC = BN / 64;

    __shared__ short sA[2][128 * 32];
    __shared__ short sB[2][BN * 32];

    const int tid  = threadIdx.x;
    const int lane = tid & 63;
    const int wave = tid >> 6;
    const int wm = wave >> 1, wn = wave & 1;

    const int nwg = gridDim.x;
    const int swz = (blockIdx.x & 7) * (nwg >> 3) + (blockIdx.x >> 3);
    const int tiles_n = N / BN;
    const int m0 = (swz / tiles_n) * 128;
    const int n0 = (swz % tiles_n) * BN;

    f32x4 acc[4][NJ];
    #pragma unroll
    for (int i = 0; i < 4; ++i)
        #pragma unroll
        for (int j = 0; j < NJ; ++j) acc[i][j] = (f32x4){0.f, 0.f, 0.f, 0.f};

    const int r = lane & 15;
    const int G = lane >> 4;

    #define GSTAGE(kt_, buf_)                                                          \
        {                                                                              \
            _Pragma("unroll")                                                          \
            for (int i = 0; i < 2; ++i) {                                              \
                int ga = (i * 4 + wave) * 64 + lane;                                   \
                int row = ga >> 2, gcol = (ga & 3) ^ (row & 3);                        \
                gload_lds16(A + (size_t)(m0 + row) * K + (kt_) + gcol * 8,             \
                            &sA[buf_][(i * 4 + wave) * 512]);                          \
            }                                                                          \
            _Pragma("unroll")                                                          \
            for (int i = 0; i < NBC; ++i) {                                            \
                int gb = (i * 4 + wave) * 64 + lane;                                   \
                int row = gb >> 2, gcol = (gb & 3) ^ (row & 3);                        \
                gload_lds16(B + (size_t)(n0 + row) * K + (kt_) + gcol * 8,             \
                            &sB[buf_][(i * 4 + wave) * 512]);                          \
            }                                                                          \
        }

    GSTAGE(0, 0);
    __syncthreads();
    int cur = 0;

    const int nsteps = K >> 5;
    for (int ks = 0; ks < nsteps; ++ks) {
        if (ks + 1 < nsteps) GSTAGE((ks + 1) * 32, cur ^ 1);

        const int sg = G ^ (r & 3);
        bf16x8 af[4], bfr[NJ];
        #pragma unroll
        for (int i = 0; i < 4; ++i) {
            int row = wm * 64 + i * 16 + r;
            af[i] = *reinterpret_cast<const bf16x8*>(&sA[cur][row * 32 + sg * 8]);
        }
        #pragma unroll
        for (int j = 0; j < NJ; ++j) {
            int row = wn * WTN + j * 16 + r;
            bfr[j] = *reinterpret_cast<const bf16x8*>(&sB[cur][row * 32 + sg * 8]);
        }
        #pragma unroll
        for (int i = 0; i < 4; ++i)
            #pragma unroll
            for (int j = 0; j < NJ; ++j)
                acc[i][j] = __builtin_amdgcn_mfma_f32_16x16x32_bf16(af[i], bfr[j], acc[i][j], 0, 0, 0);

        __syncthreads();
        cur ^= 1;
    }
    #undef GSTAGE

    const int col_l = lane & 15;
    const int row_g = (lane >> 4) * 4;
    #pragma unroll
    for (int i = 0; i < 4; ++i) {
        #pragma unroll
        for (int j = 0; j < NJ; ++j) {
            int nn = n0 + wn * WTN + j * 16 + col_l;
            float bv = bias[nn];
            float scl = (OUT_MODE == 2 && nn < HID) ? QSCL : 1.0f;
            #pragma unroll
            for (int reg = 0; reg < 4; ++reg) {
                int mm = m0 + wm * 64 + i * 16 + row_g + reg;
                float v = (acc[i][j][reg] + bv) * scl;
                if (OUT_MODE == 0) {
                    reinterpret_cast<float*>(Cout)[(size_t)mm * N + nn] = v;
                } else {
                    reinterpret_cast<unsigned short*>(Cout)[(size_t)mm * N + nn] = f2bf(v);
                }
            }
        }
    }
}

// ---------- transpose V part of qkv -> vP [bh][T][d][j] (PV-fragment order) ----------
// (unchanged from R11 -- verified)
#define TLDP 72
__global__ __launch_bounds__(256) void transpose_v(const short* __restrict__ qkv,
                                                   short* __restrict__ vP) {
    const int st = blockIdx.x;   // 64-token stripe = 2 T-tiles
    const int bh = blockIdx.y;
    const int b  = bh >> 4, h = bh & 15;
    __shared__ short ld[64 * TLDP];   // [tok_local][d]
    const int tid = threadIdx.x;

    #pragma unroll
    for (int i = 0; i < 2; ++i) {
        int idx = i * 256 + tid;
        int row = idx >> 3, c = idx & 7;
        int4 v = *reinterpret_cast<const int4*>(
            qkv + ((size_t)(b * SEQ + st * 64 + row)) * QKV_N + 2 * HID + h * DHEAD + c * 8);
        *reinterpret_cast<int4*>(&ld[row * TLDP + c * 8]) = v;
    }
    __syncthreads();
    #pragma unroll
    for (int i = 0; i < 2; ++i) {
        int u  = i * 256 + tid;        // 0..511
        int Tp = u >> 8;               // 0..1
        int d  = (u >> 2) & 63;
        int p  = u & 3;                // granule = slot group j = 8p..8p+7
        int b0 = Tp * 32 + 4 * p;      // e<4  -> tok_local = b0 + e
        int b1 = b0 + 16;              // e>=4 -> tok_local = b1 + (e-4)
        ushort4 o0, o1;
        o0.x = (unsigned short)ld[(b0 + 0) * TLDP + d];
        o0.y = (unsigned short)ld[(b0 + 1) * TLDP + d];
        o0.z = (unsigned short)ld[(b0 + 2) * TLDP + d];
        o0.w = (unsigned short)ld[(b0 + 3) * TLDP + d];
        o1.x = (unsigned short)ld[(b1 + 0) * TLDP + d];
        o1.y = (unsigned short)ld[(b1 + 1) * TLDP + d];
        o1.z = (unsigned short)ld[(b1 + 2) * TLDP + d];
        o1.w = (unsigned short)ld[(b1 + 3) * TLDP + d];
        size_t out = ((size_t)((bh * 64 + st * 2 + Tp) * 64 + d)) * 32 + p * 8;
        *reinterpret_cast<ushort4*>(&vP[out])     = o0;
        *reinterpret_cast<ushort4*>(&vP[out + 4]) = o1;
    }
}

// ---------- flash attention (causal): 8-wave kv-split + refill + tree combine ----------
// R13 diagnosis: all 1024 4-wave blocks co-resident -> no refill; unequal block work
// makes per-CU residency decay 4->1 wave/SIMD (Occupancy 17.5%) with the latency
// chain exposed at the tail. R14: block = 512 thr = 8 waves, kv split stride-8, grid
// 1024 -> only 2 blocks/CU resident (VGPR/thread caps) + 512 QUEUED -> dynamic LPT
// refill keeps 4 waves/SIMD flat. Combine = 3-round tree via comb[4][64][68] (69.6KB
// LDS, 4 barriers, once per block). Tile body byte-identical to R13 (verified).
__global__ __launch_bounds__(512) void attn_fwd(const short* __restrict__ qkv,
                                                const short* __restrict__ vP,
                                                short* __restrict__ av) {
    const int bid = blockIdx.x;
    const int qb  = 31 - (bid >> 5);     // 0..31, heaviest blocks dispatched first
    const int bh  = bid & 31;            // bid%8 == bh%8 -> per-head XCD affinity
    const int b   = bh >> 4;
    const int h   = bh & 15;

    __shared__ float comb[4][64][68];    // tree-combine buffers

    const int tid  = threadIdx.x;
    const int lane = tid & 63;
    const int wave = tid >> 6;           // 0..7 (kv-split)
    const int r    = lane & 15;
    const int G    = lane >> 4;
    const int row_g = G * 4;

    const int qbw = qb * 64;             // first q row of this block

    // Q fragments for 4 mi (pre-scaled by QSCL); B-frag: col = q = r, k = d
    bf16x8 qf[4][2];
    #pragma unroll
    for (int mi = 0; mi < 4; ++mi) {
        const short* Qg = qkv + ((size_t)(b * SEQ + qbw + mi * 16 + r)) * QKV_N + h * DHEAD;
        qf[mi][0] = *reinterpret_cast<const bf16x8*>(Qg + G * 8);
        qf[mi][1] = *reinterpret_cast<const bf16x8*>(Qg + 32 + G * 8);
    }

    f32x4 oacc[4][4];
    f32x4 oL[4];
    #pragma unroll
    for (int mi = 0; mi < 4; ++mi) {
        oL[mi] = (f32x4){0.f, 0.f, 0.f, 0.f};
        #pragma unroll
        for (int dg = 0; dg < 4; ++dg) oacc[mi][dg] = (f32x4){0.f, 0.f, 0.f, 0.f};
    }

    bf16x8 ones;
    #pragma unroll
    for (int e = 0; e < 8; ++e) ones[e] = (short)0x3f80;   // bf16 1.0

    // per-lane base pointers (strength-reduced; stride = 8 tiles of 32 kv)
    const short* kpt = qkv + (size_t)(b * SEQ + wave * 32) * QKV_N + HID + h * DHEAD
                       + r * QKV_N + G * 8;
    const short* vpt = vP + (size_t)(bh * 64 + wave) * 2048 + r * 32 + G * 8;
    const ptrdiff_t KSTEP = (ptrdiff_t)256 * QKV_N;            // 8 tiles x 32 kv rows
    const ptrdiff_t VSTEP = 8 * 2048;
    const int KG1 = 16 * QKV_N;                                // +16 kv rows (g=1)

    const int tlast = 2 * qb + 1;
    for (int t = wave; t <= tlast; t += 8) {
        int4 k00 = *reinterpret_cast<const int4*>(kpt);
        int4 k01 = *reinterpret_cast<const int4*>(kpt + 32);
        int4 k10 = *reinterpret_cast<const int4*>(kpt + KG1);
        int4 k11 = *reinterpret_cast<const int4*>(kpt + KG1 + 32);
        int4 v0 = *reinterpret_cast<const int4*>(vpt);
        int4 v1 = *reinterpret_cast<const int4*>(vpt + 16 * 32);
        int4 v2 = *reinterpret_cast<const int4*>(vpt + 32 * 32);
        int4 v3 = *reinterpret_cast<const int4*>(vpt + 48 * 32);
        kpt += KSTEP;
        vpt += VSTEP;

        bf16x8 kb[2][2], vb[4];
        __builtin_memcpy(&kb[0][0], &k00, 16);
        __builtin_memcpy(&kb[0][1], &k01, 16);
        __builtin_memcpy(&kb[1][0], &k10, 16);
        __builtin_memcpy(&kb[1][1], &k11, 16);
        __builtin_memcpy(&vb[0], &v0, 16);
        __builtin_memcpy(&vb[1], &v1, 16);
        __builtin_memcpy(&vb[2], &v2, 16);
        __builtin_memcpy(&vb[3], &v3, 16);

        const bool band = (t >= 2 * qb);    // only last two tiles cross the diagonal

        #pragma unroll
        for (int mi = 0; mi < 4; ++mi) {
            // S^T = K @ Q^T: D col = q = r (lane-local), row(reg) = kv = g*16 + 4G + reg
            f32x4 s[2];
            #pragma unroll
            for (int g = 0; g < 2; ++g) {
                f32x4 z = (f32x4){0.f, 0.f, 0.f, 0.f};
                z = __builtin_amdgcn_mfma_f32_16x16x32_bf16(kb[g][0], qf[mi][0], z, 0, 0, 0);
                z = __builtin_amdgcn_mfma_f32_16x16x32_bf16(kb[g][1], qf[mi][1], z, 0, 0, 0);
                s[g] = z;
            }
            if (band) {
                int qg = qbw + mi * 16 + r;              // global q row
                #pragma unroll
                for (int g = 0; g < 2; ++g) {
                    #pragma unroll
                    for (int reg = 0; reg < 4; ++reg) {
                        int kvg = t * 32 + g * 16 + row_g + reg;   // global kv
                        if (kvg > qg) s[g][reg] = -30000.f;
                    }
                }
            }
            // P = exp2(S) -> packed bf16 B-fragment (round-half-up pack, elem0 low 16)
            float p0 = __builtin_amdgcn_exp2f(s[0][0]);
            float p1 = __builtin_amdgcn_exp2f(s[0][1]);
            float p2 = __builtin_amdgcn_exp2f(s[0][2]);
            float p3 = __builtin_amdgcn_exp2f(s[0][3]);
            float p4 = __builtin_amdgcn_exp2f(s[1][0]);
            float p5 = __builtin_amdgcn_exp2f(s[1][1]);
            float p6 = __builtin_amdgcn_exp2f(s[1][2]);
            float p7 = __builtin_amdgcn_exp2f(s[1][3]);
            unsigned int w0 = pack_bf16_rh(p0, p1);
            unsigned int w1 = pack_bf16_rh(p2, p3);
            unsigned int w2 = pack_bf16_rh(p4, p5);
            unsigned int w3 = pack_bf16_rh(p6, p7);
            bf16x8 pb;
            { int4 f; f.x = (int)w0; f.y = (int)w1; f.z = (int)w2; f.w = (int)w3;
              __builtin_memcpy(&pb, &f, 16); }

            // O += V' @ P' : D col = q = r, row = d = dg*16 + 4G + reg
            #pragma unroll
            for (int dg = 0; dg < 4; ++dg)
                oacc[mi][dg] = __builtin_amdgcn_mfma_f32_16x16x32_bf16(vb[dg], pb, oacc[mi][dg], 0, 0, 0);
            oL[mi] = __builtin_amdgcn_mfma_f32_16x16x32_bf16(ones, pb, oL[mi], 0, 0, 0);
        }
    }

    // ---- tree combine (pure sums over kv, no-max softmax) ----
    #define CSTORE(bi_)                                                                 \
        {                                                                               \
            _Pragma("unroll")                                                           \
            for (int mi = 0; mi < 4; ++mi) {                                            \
                _Pragma("unroll")                                                       \
                for (int dg = 0; dg < 4; ++dg)                                          \
                    *reinterpret_cast<f32x4*>(&comb[bi_][mi * 16 + r][dg * 16 + row_g]) \
                        = oacc[mi][dg];                                                 \
                if (G == 0) comb[bi_][mi * 16 + r][64] = oL[mi][0];                     \
            }                                                                           \
        }
    #define CADD(bi_)                                                                   \
        {                                                                               \
            _Pragma("unroll")                                                           \
            for (int mi = 0; mi < 4; ++mi) {                                            \
                _Pragma("unroll")                                                       \
                for (int dg = 0; dg < 4; ++dg) {                                        \
                    f32x4 c = *reinterpret_cast<f32x4*>(                                \
                        &comb[bi_][mi * 16 + r][dg * 16 + row_g]);                      \
                    oacc[mi][dg] = oacc[mi][dg] + c;                                    \
                }                                                                       \
                oL[mi][0] += comb[bi_][mi * 16 + r][64];                                \
            }                                                                           \
        }

    __syncthreads();
    if (wave >= 4) CSTORE(wave - 4);                 // bufs 0..3 <- waves 4..7
    __syncthreads();
    if (wave < 4) {
        CADD(wave);                                  // wave w += wave w+4
        if (wave >= 2) CSTORE(wave);                 // bufs 2,3 <- pair sums
    }
    __syncthreads();
    if (wave < 2) {
        CADD(wave + 2);                              // wave w += pair (w+2)
        if (wave == 1) CSTORE(1);                    // buf 1 <- sum {1,5,3,7}
    }
    __syncthreads();
    if (wave == 0) {
        CADD(1);                                     // full sum of 8 waves
        #pragma unroll
        for (int mi = 0; mi < 4; ++mi) {
            float il = 1.0f / oL[mi][0];
            size_t tok = (size_t)(b * SEQ + qbw + mi * 16 + r);
            #pragma unroll
            for (int dg = 0; dg < 4; ++dg) {
                ushort4 o;
                o.x = f2bf(oacc[mi][dg][0] * il);
                o.y = f2bf(oacc[mi][dg][1] * il);
                o.z = f2bf(oacc[mi][dg][2] * il);
                o.w = f2bf(oacc[mi][dg][3] * il);
                *reinterpret_cast<ushort4*>(&av[tok * HID + h * DHEAD + dg * 16 + row_g]) = o;
            }
        }
    }
    #undef CSTORE
    #undef CADD
}

extern "C" void kernel_launch(void* const* d_in, const int* in_sizes, int n_in,
                              void* d_out, int out_size, void* d_ws, size_t ws_size,
                              hipStream_t stream) {
    const float* x     = (const float*)d_in[0];
    const float* W_qkv = (const float*)d_in[1];
    const float* b_qkv = (const float*)d_in[2];
    const float* W_o   = (const float*)d_in[3];
    const float* b_o   = (const float*)d_in[4];
    float* out = (float*)d_out;

    const int n_x    = NTOK * HID;
    const int n_wqkv = QKV_N * HID;
    const int n_wo   = HID * HID;
    const int n_qkv  = NTOK * QKV_N;
    const int n_av   = NTOK * HID;

    short* xb    = (short*)d_ws;
    short* wqkvb = xb + n_x;
    short* wob   = wqkvb + n_wqkv;
    short* qkv   = wob + n_wo;
    short* av    = qkv + n_qkv;
    short* vP    = av + n_av;

    cast_f32_bf16<<<n_x / 1024,    256, 0, stream>>>(x,     (unsigned short*)xb,    n_x / 4);
    cast_f32_bf16<<<n_wqkv / 1024, 256, 0, stream>>>(W_qkv, (unsigned short*)wqkvb, n_wqkv / 4);
    cast_f32_bf16<<<n_wo / 1024,   256, 0, stream>>>(W_o,   (unsigned short*)wob,   n_wo / 4);

    // qkv = x @ W_qkv^T + b_qkv  -> bf16 [4096][3072], Q columns pre-scaled by QSCL
    gemm_bt<128, 2><<<(NTOK / 128) * (QKV_N / 128), 256, 0, stream>>>(
        xb, wqkvb, b_qkv, (void*)qkv, NTOK, QKV_N, HID);

    // vP [32 bh][64 T][64 d][32 j] (PV-fragment order)
    transpose_v<<<dim3(SEQ / 64, BATCH * NHEAD), 256, 0, stream>>>(qkv, vP);

    // attention -> av bf16 [4096][1024]; 1024 blocks x 8 waves (2/CU + refill queue)
    attn_fwd<<<1024, 512, 0, stream>>>(qkv, vP, av);

    // out = av @ W_o^T + b_o  -> fp32
    gemm_bt<64, 0><<<(NTOK / 128) * (HID / 64), 256, 0, stream>>>(
        av, wob, b_o, (void*)out, NTOK, HID, HID);
}

// Round 15
// 115.850 us; speedup vs baseline: 1.0954x; 1.0954x over previous
//
#include <hip/hip_runtime.h>
#include <cstdint>
#include <cstddef>

// ---------- constants for this problem ----------
#define BATCH 2
#define SEQ   2048
#define HID   1024
#define NHEAD 16
#define DHEAD 64
#define QKV_N 3072   // 3*HID
#define NTOK  4096   // BATCH*SEQ

typedef __attribute__((ext_vector_type(4))) float f32x4;
typedef __attribute__((ext_vector_type(8))) short bf16x8;

#define QSCL 0.18033688011112042f   // (1/8) * log2(e), folded into Q at GEMM epilogue

__device__ inline unsigned short f2bf(float f) {
    union { float f; unsigned int u; } v; v.f = f;
    unsigned int u = v.u;
    unsigned int r = (u + 0x7fffu + ((u >> 16) & 1u)) >> 16;
    return (unsigned short)r;
}

// pack two positive floats to bf16 pair (round-half-up): P in [0,1], no NaN/inf.
__device__ __forceinline__ unsigned int pack_bf16_rh(float a, float b) {
    union { float f; unsigned int u; } ua, ub;
    ua.f = a; ub.f = b;
    return ((ua.u + 0x8000u) >> 16) | ((ub.u + 0x8000u) & 0xffff0000u);
}

__device__ __forceinline__ void gload_lds16(const void* g, void* l) {
    __builtin_amdgcn_global_load_lds(
        (const __attribute__((address_space(1))) void*)g,
        (__attribute__((address_space(3))) void*)l, 16, 0, 0);
}

// ---------- cast fp32 -> bf16 (packed ushort4) ----------
__global__ void cast_f32_bf16(const float* __restrict__ in, unsigned short* __restrict__ out, int n4) {
    int i = blockIdx.x * blockDim.x + threadIdx.x;
    if (i >= n4) return;
    float4 v = reinterpret_cast<const float4*>(in)[i];
    ushort4 o;
    o.x = f2bf(v.x); o.y = f2bf(v.y); o.z = f2bf(v.z); o.w = f2bf(v.w);
    reinterpret_cast<ushort4*>(out)[i] = o;
}

// ---------- GEMM, 2-phase dbuf pipeline, BK=64: C = A @ B^T + bias ----------
// R15: BK 32 -> 64 (m97 K-step geometry + R5's verified prefetch-before-compute).
// 16 K-steps, ONE barrier each, 32 MFMA/wave between barriers (was 16), granule
// XOR-involution (gcol = g ^ (row&7)) on both source and read -- same pattern as
// attn's sK (verified conflict-free). LDS: 2*128*64*2B*2(A,B) = 64KB at BN=128.
// OUT_MODE: 0 = fp32 row-major; 2 = bf16 row-major with Q-scale for nn < HID.
template<int BN, int OUT_MODE>
__global__ __launch_bounds__(256) void gemm_bt(const short* __restrict__ A,
                                               const short* __restrict__ B,
                                               const float* __restrict__ bias,
                                               void* __restrict__ Cout,
                                               int M, int N, int K) {
    constexpr int WTN = BN / 2;        // wave tile N
    constexpr int NJ  = WTN / 16;      // N frags per wave
    constexpr int NBC = BN / 32;       // B stage issues per thread (BK=64)

    __shared__ short sA[2][128 * 64];
    __shared__ short sB[2][BN * 64];

    const int tid  = threadIdx.x;
    const int lane = tid & 63;
    const int wave = tid >> 6;
    const int wm = wave >> 1, wn = wave & 1;

    const int nwg = gridDim.x;
    const int swz = (blockIdx.x & 7) * (nwg >> 3) + (blockIdx.x >> 3);
    const int tiles_n = N / BN;
    const int m0 = (swz / tiles_n) * 128;
    const int n0 = (swz % tiles_n) * BN;

    f32x4 acc[4][NJ];
    #pragma unroll
    for (int i = 0; i < 4; ++i)
        #pragma unroll
        for (int j = 0; j < NJ; ++j) acc[i][j] = (f32x4){0.f, 0.f, 0.f, 0.f};

    const int r = lane & 15;
    const int G = lane >> 4;

    // stage: granule g (8 shorts) -> row = g>>3, lcol = g&7, source col = lcol^(row&7)
    #define GSTAGE(kt_, buf_)                                                          \
        {                                                                              \
            _Pragma("unroll")                                                          \
            for (int i = 0; i < 4; ++i) {                                              \
                int ga = (i * 4 + wave) * 64 + lane;                                   \
                int row = ga >> 3, gcol = (ga & 7) ^ (row & 7);                        \
                gload_lds16(A + (size_t)(m0 + row) * K + (kt_) + gcol * 8,             \
                            &sA[buf_][(i * 4 + wave) * 512]);                          \
            }                                                                          \
            _Pragma("unroll")                                                          \
            for (int i = 0; i < NBC; ++i) {                                            \
                int gb = (i * 4 + wave) * 64 + lane;                                   \
                int row = gb >> 3, gcol = (gb & 7) ^ (row & 7);                        \
                gload_lds16(B + (size_t)(n0 + row) * K + (kt_) + gcol * 8,             \
                            &sB[buf_][(i * 4 + wave) * 512]);                          \
            }                                                                          \
        }

    GSTAGE(0, 0);
    __syncthreads();   // implicit vmcnt(0): step 0 landed
    int cur = 0;

    const int nsteps = K >> 6;
    for (int ks = 0; ks < nsteps; ++ks) {
        if (ks + 1 < nsteps) GSTAGE((ks + 1) * 64, cur ^ 1);   // prefetch next step

        #pragma unroll
        for (int kk = 0; kk < 2; ++kk) {
            bf16x8 af[4], bfr[NJ];
            #pragma unroll
            for (int i = 0; i < 4; ++i) {
                int row = wm * 64 + i * 16 + r;
                int sg  = (kk * 4 + G) ^ (row & 7);
                af[i] = *reinterpret_cast<const bf16x8*>(&sA[cur][row * 64 + sg * 8]);
            }
            #pragma unroll
            for (int j = 0; j < NJ; ++j) {
                int row = wn * WTN + j * 16 + r;
                int sg  = (kk * 4 + G) ^ (row & 7);
                bfr[j] = *reinterpret_cast<const bf16x8*>(&sB[cur][row * 64 + sg * 8]);
            }
            #pragma unroll
            for (int i = 0; i < 4; ++i)
                #pragma unroll
                for (int j = 0; j < NJ; ++j)
                    acc[i][j] = __builtin_amdgcn_mfma_f32_16x16x32_bf16(af[i], bfr[j], acc[i][j], 0, 0, 0);
        }

        __syncthreads();   // drains vmcnt: prefetch landed; cur free for overwrite
        cur ^= 1;
    }
    #undef GSTAGE

    // epilogue: D layout col=lane&15, row=4*(lane>>4)+reg
    const int col_l = lane & 15;
    const int row_g = (lane >> 4) * 4;
    #pragma unroll
    for (int i = 0; i < 4; ++i) {
        #pragma unroll
        for (int j = 0; j < NJ; ++j) {
            int nn = n0 + wn * WTN + j * 16 + col_l;
            float bv = bias[nn];
            float scl = (OUT_MODE == 2 && nn < HID) ? QSCL : 1.0f;
            #pragma unroll
            for (int reg = 0; reg < 4; ++reg) {
                int mm = m0 + wm * 64 + i * 16 + row_g + reg;
                float v = (acc[i][j][reg] + bv) * scl;
                if (OUT_MODE == 0) {
                    reinterpret_cast<float*>(Cout)[(size_t)mm * N + nn] = v;
                } else {
                    reinterpret_cast<unsigned short*>(Cout)[(size_t)mm * N + nn] = f2bf(v);
                }
            }
        }
    }
}

// ---------- transpose V part of qkv -> vP [bh][T][d][j] (PV-fragment order) ----------
// (unchanged from R11 -- verified)
#define TLDP 72
__global__ __launch_bounds__(256) void transpose_v(const short* __restrict__ qkv,
                                                   short* __restrict__ vP) {
    const int st = blockIdx.x;   // 64-token stripe = 2 T-tiles
    const int bh = blockIdx.y;
    const int b  = bh >> 4, h = bh & 15;
    __shared__ short ld[64 * TLDP];   // [tok_local][d]
    const int tid = threadIdx.x;

    #pragma unroll
    for (int i = 0; i < 2; ++i) {
        int idx = i * 256 + tid;
        int row = idx >> 3, c = idx & 7;
        int4 v = *reinterpret_cast<const int4*>(
            qkv + ((size_t)(b * SEQ + st * 64 + row)) * QKV_N + 2 * HID + h * DHEAD + c * 8);
        *reinterpret_cast<int4*>(&ld[row * TLDP + c * 8]) = v;
    }
    __syncthreads();
    #pragma unroll
    for (int i = 0; i < 2; ++i) {
        int u  = i * 256 + tid;        // 0..511
        int Tp = u >> 8;               // 0..1
        int d  = (u >> 2) & 63;
        int p  = u & 3;                // granule = slot group j = 8p..8p+7
        int b0 = Tp * 32 + 4 * p;      // e<4  -> tok_local = b0 + e
        int b1 = b0 + 16;              // e>=4 -> tok_local = b1 + (e-4)
        ushort4 o0, o1;
        o0.x = (unsigned short)ld[(b0 + 0) * TLDP + d];
        o0.y = (unsigned short)ld[(b0 + 1) * TLDP + d];
        o0.z = (unsigned short)ld[(b0 + 2) * TLDP + d];
        o0.w = (unsigned short)ld[(b0 + 3) * TLDP + d];
        o1.x = (unsigned short)ld[(b1 + 0) * TLDP + d];
        o1.y = (unsigned short)ld[(b1 + 1) * TLDP + d];
        o1.z = (unsigned short)ld[(b1 + 2) * TLDP + d];
        o1.w = (unsigned short)ld[(b1 + 3) * TLDP + d];
        size_t out = ((size_t)((bh * 64 + st * 2 + Tp) * 64 + d)) * 32 + p * 8;
        *reinterpret_cast<ushort4*>(&vP[out])     = o0;
        *reinterpret_cast<ushort4*>(&vP[out + 4]) = o1;
    }
}

// ---------- flash attention (causal): R13 verified kernel (48 us), byte-identical ----------
__global__ __launch_bounds__(256) void attn_fwd(const short* __restrict__ qkv,
                                                const short* __restrict__ vP,
                                                short* __restrict__ av) {
    const int bid = blockIdx.x;
    const int qb  = 31 - (bid >> 5);     // 0..31, heaviest blocks dispatched first
    const int bh  = bid & 31;            // bid%8 == bh%8 -> per-head XCD affinity
    const int b   = bh >> 4;
    const int h   = bh & 15;

    __shared__ float comb[64][68];       // cols 0..63 = O[q][d], col 64 = L[q]

    const int tid  = threadIdx.x;
    const int lane = tid & 63;
    const int wave = tid >> 6;           // 0..3 (kv-split)
    const int r    = lane & 15;
    const int G    = lane >> 4;
    const int row_g = G * 4;

    const int qbw = qb * 64;             // first q row of this block

    // Q fragments for 4 mi (pre-scaled by QSCL); B-frag: col = q = r, k = d
    bf16x8 qf[4][2];
    #pragma unroll
    for (int mi = 0; mi < 4; ++mi) {
        const short* Qg = qkv + ((size_t)(b * SEQ + qbw + mi * 16 + r)) * QKV_N + h * DHEAD;
        qf[mi][0] = *reinterpret_cast<const bf16x8*>(Qg + G * 8);
        qf[mi][1] = *reinterpret_cast<const bf16x8*>(Qg + 32 + G * 8);
    }

    f32x4 oacc[4][4];
    f32x4 oL[4];
    #pragma unroll
    for (int mi = 0; mi < 4; ++mi) {
        oL[mi] = (f32x4){0.f, 0.f, 0.f, 0.f};
        #pragma unroll
        for (int dg = 0; dg < 4; ++dg) oacc[mi][dg] = (f32x4){0.f, 0.f, 0.f, 0.f};
    }

    bf16x8 ones;
    #pragma unroll
    for (int e = 0; e < 8; ++e) ones[e] = (short)0x3f80;   // bf16 1.0

    // per-lane base pointers (strength-reduced: incremented each iteration)
    const short* kpt = qkv + (size_t)(b * SEQ + wave * 32) * QKV_N + HID + h * DHEAD
                       + r * QKV_N + G * 8;                    // kv row g=0 fragment base
    const short* vpt = vP + (size_t)(bh * 64 + wave) * 2048 + r * 32 + G * 8;
    const ptrdiff_t KSTEP = (ptrdiff_t)128 * QKV_N;            // 4 tiles of 32 kv
    const ptrdiff_t VSTEP = 4 * 2048;
    const int KG1 = 16 * QKV_N;                                // +16 kv rows (g=1)

    const int tlast = 2 * qb + 1;
    for (int t = wave; t <= tlast; t += 4) {
        int4 k00 = *reinterpret_cast<const int4*>(kpt);
        int4 k01 = *reinterpret_cast<const int4*>(kpt + 32);
        int4 k10 = *reinterpret_cast<const int4*>(kpt + KG1);
        int4 k11 = *reinterpret_cast<const int4*>(kpt + KG1 + 32);
        int4 v0 = *reinterpret_cast<const int4*>(vpt);
        int4 v1 = *reinterpret_cast<const int4*>(vpt + 16 * 32);
        int4 v2 = *reinterpret_cast<const int4*>(vpt + 32 * 32);
        int4 v3 = *reinterpret_cast<const int4*>(vpt + 48 * 32);
        kpt += KSTEP;
        vpt += VSTEP;

        bf16x8 kb[2][2], vb[4];
        __builtin_memcpy(&kb[0][0], &k00, 16);
        __builtin_memcpy(&kb[0][1], &k01, 16);
        __builtin_memcpy(&kb[1][0], &k10, 16);
        __builtin_memcpy(&kb[1][1], &k11, 16);
        __builtin_memcpy(&vb[0], &v0, 16);
        __builtin_memcpy(&vb[1], &v1, 16);
        __builtin_memcpy(&vb[2], &v2, 16);
        __builtin_memcpy(&vb[3], &v3, 16);

        const bool band = (t >= 2 * qb);    // only last two tiles cross the diagonal

        #pragma unroll
        for (int mi = 0; mi < 4; ++mi) {
            // S^T = K @ Q^T: D col = q = r (lane-local), row(reg) = kv = g*16 + 4G + reg
            f32x4 s[2];
            #pragma unroll
            for (int g = 0; g < 2; ++g) {
                f32x4 z = (f32x4){0.f, 0.f, 0.f, 0.f};
                z = __builtin_amdgcn_mfma_f32_16x16x32_bf16(kb[g][0], qf[mi][0], z, 0, 0, 0);
                z = __builtin_amdgcn_mfma_f32_16x16x32_bf16(kb[g][1], qf[mi][1], z, 0, 0, 0);
                s[g] = z;
            }
            if (band) {
                int qg = qbw + mi * 16 + r;              // global q row
                #pragma unroll
                for (int g = 0; g < 2; ++g) {
                    #pragma unroll
                    for (int reg = 0; reg < 4; ++reg) {
                        int kvg = t * 32 + g * 16 + row_g + reg;   // global kv
                        if (kvg > qg) s[g][reg] = -30000.f;
                    }
                }
            }
            // P = exp2(S) -> packed bf16 B-fragment (round-half-up pack, elem0 low 16)
            float p0 = __builtin_amdgcn_exp2f(s[0][0]);
            float p1 = __builtin_amdgcn_exp2f(s[0][1]);
            float p2 = __builtin_amdgcn_exp2f(s[0][2]);
            float p3 = __builtin_amdgcn_exp2f(s[0][3]);
            float p4 = __builtin_amdgcn_exp2f(s[1][0]);
            float p5 = __builtin_amdgcn_exp2f(s[1][1]);
            float p6 = __builtin_amdgcn_exp2f(s[1][2]);
            float p7 = __builtin_amdgcn_exp2f(s[1][3]);
            unsigned int w0 = pack_bf16_rh(p0, p1);
            unsigned int w1 = pack_bf16_rh(p2, p3);
            unsigned int w2 = pack_bf16_rh(p4, p5);
            unsigned int w3 = pack_bf16_rh(p6, p7);
            bf16x8 pb;
            { int4 f; f.x = (int)w0; f.y = (int)w1; f.z = (int)w2; f.w = (int)w3;
              __builtin_memcpy(&pb, &f, 16); }

            // O += V' @ P' : D col = q = r, row = d = dg*16 + 4G + reg
            #pragma unroll
            for (int dg = 0; dg < 4; ++dg)
                oacc[mi][dg] = __builtin_amdgcn_mfma_f32_16x16x32_bf16(vb[dg], pb, oacc[mi][dg], 0, 0, 0);
            oL[mi] = __builtin_amdgcn_mfma_f32_16x16x32_bf16(ones, pb, oL[mi], 0, 0, 0);
        }
    }

    // ---- combine (pure sums over kv, no-max softmax): 3-barrier serial LDS add ----
    __syncthreads();
    if (wave == 0) {
        #pragma unroll
        for (int mi = 0; mi < 4; ++mi) {
            #pragma unroll
            for (int dg = 0; dg < 4; ++dg)
                *reinterpret_cast<f32x4*>(&comb[mi * 16 + r][dg * 16 + row_g]) = oacc[mi][dg];
            if (G == 0) comb[mi * 16 + r][64] = oL[mi][0];
        }
    }
    __syncthreads();
    if (wave == 1) {
        #pragma unroll
        for (int mi = 0; mi < 4; ++mi) {
            #pragma unroll
            for (int dg = 0; dg < 4; ++dg) {
                f32x4 c = *reinterpret_cast<f32x4*>(&comb[mi * 16 + r][dg * 16 + row_g]);
                *reinterpret_cast<f32x4*>(&comb[mi * 16 + r][dg * 16 + row_g]) = c + oacc[mi][dg];
            }
            if (G == 0) comb[mi * 16 + r][64] += oL[mi][0];
        }
    }
    __syncthreads();
    if (wave == 2) {
        #pragma unroll
        for (int mi = 0; mi < 4; ++mi) {
            #pragma unroll
            for (int dg = 0; dg < 4; ++dg) {
                f32x4 c = *reinterpret_cast<f32x4*>(&comb[mi * 16 + r][dg * 16 + row_g]);
                *reinterpret_cast<f32x4*>(&comb[mi * 16 + r][dg * 16 + row_g]) = c + oacc[mi][dg];
            }
            if (G == 0) comb[mi * 16 + r][64] += oL[mi][0];
        }
    }
    __syncthreads();
    if (wave == 3) {
        #pragma unroll
        for (int mi = 0; mi < 4; ++mi) {
            float l = comb[mi * 16 + r][64] + oL[mi][0];
            float il = 1.0f / l;
            size_t tok = (size_t)(b * SEQ + qbw + mi * 16 + r);
            #pragma unroll
            for (int dg = 0; dg < 4; ++dg) {
                f32x4 tot = *reinterpret_cast<f32x4*>(&comb[mi * 16 + r][dg * 16 + row_g]);
                tot = tot + oacc[mi][dg];
                ushort4 o;
                o.x = f2bf(tot[0] * il);
                o.y = f2bf(tot[1] * il);
                o.z = f2bf(tot[2] * il);
                o.w = f2bf(tot[3] * il);
                *reinterpret_cast<ushort4*>(&av[tok * HID + h * DHEAD + dg * 16 + row_g]) = o;
            }
        }
    }
}

extern "C" void kernel_launch(void* const* d_in, const int* in_sizes, int n_in,
                              void* d_out, int out_size, void* d_ws, size_t ws_size,
                              hipStream_t stream) {
    const float* x     = (const float*)d_in[0];
    const float* W_qkv = (const float*)d_in[1];
    const float* b_qkv = (const float*)d_in[2];
    const float* W_o   = (const float*)d_in[3];
    const float* b_o   = (const float*)d_in[4];
    float* out = (float*)d_out;

    const int n_x    = NTOK * HID;
    const int n_wqkv = QKV_N * HID;
    const int n_wo   = HID * HID;
    const int n_qkv  = NTOK * QKV_N;
    const int n_av   = NTOK * HID;

    short* xb    = (short*)d_ws;
    short* wqkvb = xb + n_x;
    short* wob   = wqkvb + n_wqkv;
    short* qkv   = wob + n_wo;
    short* av    = qkv + n_qkv;
    short* vP    = av + n_av;

    cast_f32_bf16<<<n_x / 1024,    256, 0, stream>>>(x,     (unsigned short*)xb,    n_x / 4);
    cast_f32_bf16<<<n_wqkv / 1024, 256, 0, stream>>>(W_qkv, (unsigned short*)wqkvb, n_wqkv / 4);
    cast_f32_bf16<<<n_wo / 1024,   256, 0, stream>>>(W_o,   (unsigned short*)wob,   n_wo / 4);

    // qkv = x @ W_qkv^T + b_qkv  -> bf16 [4096][3072], Q columns pre-scaled by QSCL
    gemm_bt<128, 2><<<(NTOK / 128) * (QKV_N / 128), 256, 0, stream>>>(
        xb, wqkvb, b_qkv, (void*)qkv, NTOK, QKV_N, HID);

    // vP [32 bh][64 T][64 d][32 j] (PV-fragment order)
    transpose_v<<<dim3(SEQ / 64, BATCH * NHEAD), 256, 0, stream>>>(qkv, vP);

    // attention -> av bf16 [4096][1024]; R13 verified (1024 blocks x 4 waves)
    attn_fwd<<<1024, 256, 0, stream>>>(qkv, vP, av);

    // out = av @ W_o^T + b_o  -> fp32
    gemm_bt<64, 0><<<(NTOK / 128) * (HID / 64), 256, 0, stream>>>(
        av, wob, b_o, (void*)out, NTOK, HID, HID);
}

// Round 16
// 114.594 us; speedup vs baseline: 1.1074x; 1.0110x over previous
//
#include <hip/hip_runtime.h>
#include <cstdint>
#include <cstddef>

// ---------- constants for this problem ----------
#define BATCH 2
#define SEQ   2048
#define HID   1024
#define NHEAD 16
#define DHEAD 64
#define QKV_N 3072   // 3*HID
#define NTOK  4096   // BATCH*SEQ

typedef __attribute__((ext_vector_type(4))) float f32x4;
typedef __attribute__((ext_vector_type(8))) short bf16x8;

#define QSCL 0.18033688011112042f   // (1/8) * log2(e), folded into Q at GEMM epilogue

__device__ inline unsigned short f2bf(float f) {
    union { float f; unsigned int u; } v; v.f = f;
    unsigned int u = v.u;
    unsigned int r = (u + 0x7fffu + ((u >> 16) & 1u)) >> 16;
    return (unsigned short)r;
}

// pack two positive floats to bf16 pair (round-half-up): P in [0,1], no NaN/inf.
__device__ __forceinline__ unsigned int pack_bf16_rh(float a, float b) {
    union { float f; unsigned int u; } ua, ub;
    ua.f = a; ub.f = b;
    return ((ua.u + 0x8000u) >> 16) | ((ub.u + 0x8000u) & 0xffff0000u);
}

__device__ __forceinline__ void gload_lds16(const void* g, void* l) {
    __builtin_amdgcn_global_load_lds(
        (const __attribute__((address_space(1))) void*)g,
        (__attribute__((address_space(3))) void*)l, 16, 0, 0);
}

// ---------- cast fp32 -> bf16 (packed ushort4) ----------
__global__ void cast_f32_bf16(const float* __restrict__ in, unsigned short* __restrict__ out, int n4) {
    int i = blockIdx.x * blockDim.x + threadIdx.x;
    if (i >= n4) return;
    float4 v = reinterpret_cast<const float4*>(in)[i];
    ushort4 o;
    o.x = f2bf(v.x); o.y = f2bf(v.y); o.z = f2bf(v.z); o.w = f2bf(v.w);
    reinterpret_cast<ushort4*>(out)[i] = o;
}

// ---------- GEMM, 2-phase dbuf pipeline, BK=32 (R5/R13 verified) ----------
template<int BN, int OUT_MODE>
__global__ __launch_bounds__(256) void gemm_bt(const short* __restrict__ A,
                                               const short* __restrict__ B,
                                               const float* __restrict__ bias,
                                               void* __restrict__ Cout,
                                               int M, int N, int K) {
    constexpr int WTN = BN / 2;
    constexpr int NJ  = WTN / 16;
    constexpr int NBC = BN / 64;

    __shared__ short sA[2][128 * 32];
    __shared__ short sB[2][BN * 32];

    const int tid  = threadIdx.x;
    const int lane = tid & 63;
    const int wave = tid >> 6;
    const int wm = wave >> 1, wn = wave & 1;

    const int nwg = gridDim.x;
    const int swz = (blockIdx.x & 7) * (nwg >> 3) + (blockIdx.x >> 3);
    const int tiles_n = N / BN;
    const int m0 = (swz / tiles_n) * 128;
    const int n0 = (swz % tiles_n) * BN;

    f32x4 acc[4][NJ];
    #pragma unroll
    for (int i = 0; i < 4; ++i)
        #pragma unroll
        for (int j = 0; j < NJ; ++j) acc[i][j] = (f32x4){0.f, 0.f, 0.f, 0.f};

    const int r = lane & 15;
    const int G = lane >> 4;

    #define GSTAGE(kt_, buf_)                                                          \
        {                                                                              \
            _Pragma("unroll")                                                          \
            for (int i = 0; i < 2; ++i) {                                              \
                int ga = (i * 4 + wave) * 64 + lane;                                   \
                int row = ga >> 2, gcol = (ga & 3) ^ (row & 3);                        \
                gload_lds16(A + (size_t)(m0 + row) * K + (kt_) + gcol * 8,             \
                            &sA[buf_][(i * 4 + wave) * 512]);                          \
            }                                                                          \
            _Pragma("unroll")                                                          \
            for (int i = 0; i < NBC; ++i) {                                            \
                int gb = (i * 4 + wave) * 64 + lane;                                   \
                int row = gb >> 2, gcol = (gb & 3) ^ (row & 3);                        \
                gload_lds16(B + (size_t)(n0 + row) * K + (kt_) + gcol * 8,             \
                            &sB[buf_][(i * 4 + wave) * 512]);                          \
            }                                                                          \
        }

    GSTAGE(0, 0);
    __syncthreads();
    int cur = 0;

    const int nsteps = K >> 5;
    for (int ks = 0; ks < nsteps; ++ks) {
        if (ks + 1 < nsteps) GSTAGE((ks + 1) * 32, cur ^ 1);

        const int sg = G ^ (r & 3);
        bf16x8 af[4], bfr[NJ];
        #pragma unroll
        for (int i = 0; i < 4; ++i) {
            int row = wm * 64 + i * 16 + r;
            af[i] = *reinterpret_cast<const bf16x8*>(&sA[cur][row * 32 + sg * 8]);
        }
        #pragma unroll
        for (int j = 0; j < NJ; ++j) {
            int row = wn * WTN + j * 16 + r;
            bfr[j] = *reinterpret_cast<const bf16x8*>(&sB[cur][row * 32 + sg * 8]);
        }
        #pragma unroll
        for (int i = 0; i < 4; ++i)
            #pragma unroll
            for (int j = 0; j < NJ; ++j)
                acc[i][j] = __builtin_amdgcn_mfma_f32_16x16x32_bf16(af[i], bfr[j], acc[i][j], 0, 0, 0);

        __syncthreads();
        cur ^= 1;
    }
    #undef GSTAGE

    const int col_l = lane & 15;
    const int row_g = (lane >> 4) * 4;
    #pragma unroll
    for (int i = 0; i < 4; ++i) {
        #pragma unroll
        for (int j = 0; j < NJ; ++j) {
            int nn = n0 + wn * WTN + j * 16 + col_l;
            float bv = bias[nn];
            float scl = (OUT_MODE == 2 && nn < HID) ? QSCL : 1.0f;
            #pragma unroll
            for (int reg = 0; reg < 4; ++reg) {
                int mm = m0 + wm * 64 + i * 16 + row_g + reg;
                float v = (acc[i][j][reg] + bv) * scl;
                if (OUT_MODE == 0) {
                    reinterpret_cast<float*>(Cout)[(size_t)mm * N + nn] = v;
                } else {
                    reinterpret_cast<unsigned short*>(Cout)[(size_t)mm * N + nn] = f2bf(v);
                }
            }
        }
    }
}

// ---------- transpose V part of qkv -> vP [bh][T][d][j] (PV-fragment order) ----------
// (unchanged from R11 -- verified)
#define TLDP 72
__global__ __launch_bounds__(256) void transpose_v(const short* __restrict__ qkv,
                                                   short* __restrict__ vP) {
    const int st = blockIdx.x;
    const int bh = blockIdx.y;
    const int b  = bh >> 4, h = bh & 15;
    __shared__ short ld[64 * TLDP];
    const int tid = threadIdx.x;

    #pragma unroll
    for (int i = 0; i < 2; ++i) {
        int idx = i * 256 + tid;
        int row = idx >> 3, c = idx & 7;
        int4 v = *reinterpret_cast<const int4*>(
            qkv + ((size_t)(b * SEQ + st * 64 + row)) * QKV_N + 2 * HID + h * DHEAD + c * 8);
        *reinterpret_cast<int4*>(&ld[row * TLDP + c * 8]) = v;
    }
    __syncthreads();
    #pragma unroll
    for (int i = 0; i < 2; ++i) {
        int u  = i * 256 + tid;
        int Tp = u >> 8;
        int d  = (u >> 2) & 63;
        int p  = u & 3;
        int b0 = Tp * 32 + 4 * p;
        int b1 = b0 + 16;
        ushort4 o0, o1;
        o0.x = (unsigned short)ld[(b0 + 0) * TLDP + d];
        o0.y = (unsigned short)ld[(b0 + 1) * TLDP + d];
        o0.z = (unsigned short)ld[(b0 + 2) * TLDP + d];
        o0.w = (unsigned short)ld[(b0 + 3) * TLDP + d];
        o1.x = (unsigned short)ld[(b1 + 0) * TLDP + d];
        o1.y = (unsigned short)ld[(b1 + 1) * TLDP + d];
        o1.z = (unsigned short)ld[(b1 + 2) * TLDP + d];
        o1.w = (unsigned short)ld[(b1 + 3) * TLDP + d];
        size_t out = ((size_t)((bh * 64 + st * 2 + Tp) * 64 + d)) * 32 + p * 8;
        *reinterpret_cast<ushort4*>(&vP[out])     = o0;
        *reinterpret_cast<ushort4*>(&vP[out + 4]) = o1;
    }
}

// ---------- flash attention (causal): pair-balanced + 2-deep pipeline + setprio ----------
// R13 body verified. R16: (1) 512 UNIFORM blocks -- each does job A (qb = 31-pi) then
// job B (qb = pi), each with 4-way kv-split and its own combine: every block = exactly
// 68 tiles -> zero tail decay, flat 2 waves/SIMD. (2) 2-deep register pipeline: tile
// t+4's K/V loads issue before tile t's compute (clamped pointers, no OOB). (3) T5
// setprio(1) around MFMA clusters.
__global__ __launch_bounds__(256, 2) void attn_fwd(const short* __restrict__ qkv,
                                                   const short* __restrict__ vP,
                                                   short* __restrict__ av) {
    const int bid = blockIdx.x;
    const int pi  = bid >> 5;            // 0..15 (pair index)
    const int bh  = bid & 31;            // bid%8 == bh%8 -> per-head XCD affinity
    const int b   = bh >> 4;
    const int h   = bh & 15;

    __shared__ float comb[64][68];       // cols 0..63 = O[q][d], col 64 = L[q]

    const int tid  = threadIdx.x;
    const int lane = tid & 63;
    const int wave = tid >> 6;           // 0..3 (kv-split)
    const int r    = lane & 15;
    const int G    = lane >> 4;
    const int row_g = G * 4;

    bf16x8 ones;
    #pragma unroll
    for (int e = 0; e < 8; ++e) ones[e] = (short)0x3f80;   // bf16 1.0

    // job-invariant per-lane K/V base pointers (kv start = wave*32)
    const short* kpt0 = qkv + (size_t)(b * SEQ + wave * 32) * QKV_N + HID + h * DHEAD
                        + r * QKV_N + G * 8;
    const short* vpt0 = vP + (size_t)(bh * 64 + wave) * 2048 + r * 32 + G * 8;
    const ptrdiff_t KSTEP = (ptrdiff_t)128 * QKV_N;            // 4 tiles of 32 kv
    const ptrdiff_t VSTEP = 4 * 2048;
    const int KG1 = 16 * QKV_N;

    #pragma unroll 1
    for (int job = 0; job < 2; ++job) {
        const int qb  = job == 0 ? 31 - pi : pi;   // heavy job first
        const int qbw = qb * 64;

        // Q fragments for 4 mi (pre-scaled by QSCL); B-frag: col = q = r, k = d
        bf16x8 qf[4][2];
        #pragma unroll
        for (int mi = 0; mi < 4; ++mi) {
            const short* Qg = qkv + ((size_t)(b * SEQ + qbw + mi * 16 + r)) * QKV_N + h * DHEAD;
            qf[mi][0] = *reinterpret_cast<const bf16x8*>(Qg + G * 8);
            qf[mi][1] = *reinterpret_cast<const bf16x8*>(Qg + 32 + G * 8);
        }

        f32x4 oacc[4][4];
        f32x4 oL[4];
        #pragma unroll
        for (int mi = 0; mi < 4; ++mi) {
            oL[mi] = (f32x4){0.f, 0.f, 0.f, 0.f};
            #pragma unroll
            for (int dg = 0; dg < 4; ++dg) oacc[mi][dg] = (f32x4){0.f, 0.f, 0.f, 0.f};
        }

        const short* kpt = kpt0;
        const short* vpt = vpt0;
        const int tlast = 2 * qb + 1;

        // preload tile t = wave (addresses always in-range: kv <= 127 < SEQ)
        int4 kc00 = *reinterpret_cast<const int4*>(kpt);
        int4 kc01 = *reinterpret_cast<const int4*>(kpt + 32);
        int4 kc10 = *reinterpret_cast<const int4*>(kpt + KG1);
        int4 kc11 = *reinterpret_cast<const int4*>(kpt + KG1 + 32);
        int4 vc0  = *reinterpret_cast<const int4*>(vpt);
        int4 vc1  = *reinterpret_cast<const int4*>(vpt + 16 * 32);
        int4 vc2  = *reinterpret_cast<const int4*>(vpt + 32 * 32);
        int4 vc3  = *reinterpret_cast<const int4*>(vpt + 48 * 32);

        for (int t = wave; t <= tlast; t += 4) {
            // issue next tile's loads (clamped: last iteration re-reads current)
            const bool more = (t + 4 <= tlast);
            const short* kn = more ? kpt + KSTEP : kpt;
            const short* vn = more ? vpt + VSTEP : vpt;
            int4 kn00 = *reinterpret_cast<const int4*>(kn);
            int4 kn01 = *reinterpret_cast<const int4*>(kn + 32);
            int4 kn10 = *reinterpret_cast<const int4*>(kn + KG1);
            int4 kn11 = *reinterpret_cast<const int4*>(kn + KG1 + 32);
            int4 vn0  = *reinterpret_cast<const int4*>(vn);
            int4 vn1  = *reinterpret_cast<const int4*>(vn + 16 * 32);
            int4 vn2  = *reinterpret_cast<const int4*>(vn + 32 * 32);
            int4 vn3  = *reinterpret_cast<const int4*>(vn + 48 * 32);
            kpt = kn; vpt = vn;

            bf16x8 kb[2][2], vb[4];
            __builtin_memcpy(&kb[0][0], &kc00, 16);
            __builtin_memcpy(&kb[0][1], &kc01, 16);
            __builtin_memcpy(&kb[1][0], &kc10, 16);
            __builtin_memcpy(&kb[1][1], &kc11, 16);
            __builtin_memcpy(&vb[0], &vc0, 16);
            __builtin_memcpy(&vb[1], &vc1, 16);
            __builtin_memcpy(&vb[2], &vc2, 16);
            __builtin_memcpy(&vb[3], &vc3, 16);

            const bool band = (t >= 2 * qb);

            #pragma unroll
            for (int mi = 0; mi < 4; ++mi) {
                // S^T = K @ Q^T: col = q = r (lane-local), row(reg) = kv = g*16+4G+reg
                f32x4 s[2];
                __builtin_amdgcn_s_setprio(1);
                #pragma unroll
                for (int g = 0; g < 2; ++g) {
                    f32x4 z = (f32x4){0.f, 0.f, 0.f, 0.f};
                    z = __builtin_amdgcn_mfma_f32_16x16x32_bf16(kb[g][0], qf[mi][0], z, 0, 0, 0);
                    z = __builtin_amdgcn_mfma_f32_16x16x32_bf16(kb[g][1], qf[mi][1], z, 0, 0, 0);
                    s[g] = z;
                }
                __builtin_amdgcn_s_setprio(0);
                if (band) {
                    int qg = qbw + mi * 16 + r;
                    #pragma unroll
                    for (int g = 0; g < 2; ++g) {
                        #pragma unroll
                        for (int reg = 0; reg < 4; ++reg) {
                            int kvg = t * 32 + g * 16 + row_g + reg;
                            if (kvg > qg) s[g][reg] = -30000.f;
                        }
                    }
                }
                // P = exp2(S) -> packed bf16 B-fragment (round-half-up, elem0 low 16)
                float p0 = __builtin_amdgcn_exp2f(s[0][0]);
                float p1 = __builtin_amdgcn_exp2f(s[0][1]);
                float p2 = __builtin_amdgcn_exp2f(s[0][2]);
                float p3 = __builtin_amdgcn_exp2f(s[0][3]);
                float p4 = __builtin_amdgcn_exp2f(s[1][0]);
                float p5 = __builtin_amdgcn_exp2f(s[1][1]);
                float p6 = __builtin_amdgcn_exp2f(s[1][2]);
                float p7 = __builtin_amdgcn_exp2f(s[1][3]);
                unsigned int w0 = pack_bf16_rh(p0, p1);
                unsigned int w1 = pack_bf16_rh(p2, p3);
                unsigned int w2 = pack_bf16_rh(p4, p5);
                unsigned int w3 = pack_bf16_rh(p6, p7);
                bf16x8 pb;
                { int4 f; f.x = (int)w0; f.y = (int)w1; f.z = (int)w2; f.w = (int)w3;
                  __builtin_memcpy(&pb, &f, 16); }

                // O += V' @ P' : col = q = r, row = d = dg*16 + 4G + reg
                __builtin_amdgcn_s_setprio(1);
                #pragma unroll
                for (int dg = 0; dg < 4; ++dg)
                    oacc[mi][dg] = __builtin_amdgcn_mfma_f32_16x16x32_bf16(vb[dg], pb, oacc[mi][dg], 0, 0, 0);
                oL[mi] = __builtin_amdgcn_mfma_f32_16x16x32_bf16(ones, pb, oL[mi], 0, 0, 0);
                __builtin_amdgcn_s_setprio(0);
            }

            kc00 = kn00; kc01 = kn01; kc10 = kn10; kc11 = kn11;
            vc0 = vn0; vc1 = vn1; vc2 = vn2; vc3 = vn3;
        }

        // ---- combine (pure sums over kv, no-max softmax): 3-barrier serial LDS add ----
        __syncthreads();
        if (wave == 0) {
            #pragma unroll
            for (int mi = 0; mi < 4; ++mi) {
                #pragma unroll
                for (int dg = 0; dg < 4; ++dg)
                    *reinterpret_cast<f32x4*>(&comb[mi * 16 + r][dg * 16 + row_g]) = oacc[mi][dg];
                if (G == 0) comb[mi * 16 + r][64] = oL[mi][0];
            }
        }
        __syncthreads();
        if (wave == 1) {
            #pragma unroll
            for (int mi = 0; mi < 4; ++mi) {
                #pragma unroll
                for (int dg = 0; dg < 4; ++dg) {
                    f32x4 c = *reinterpret_cast<f32x4*>(&comb[mi * 16 + r][dg * 16 + row_g]);
                    *reinterpret_cast<f32x4*>(&comb[mi * 16 + r][dg * 16 + row_g]) = c + oacc[mi][dg];
                }
                if (G == 0) comb[mi * 16 + r][64] += oL[mi][0];
            }
        }
        __syncthreads();
        if (wave == 2) {
            #pragma unroll
            for (int mi = 0; mi < 4; ++mi) {
                #pragma unroll
                for (int dg = 0; dg < 4; ++dg) {
                    f32x4 c = *reinterpret_cast<f32x4*>(&comb[mi * 16 + r][dg * 16 + row_g]);
                    *reinterpret_cast<f32x4*>(&comb[mi * 16 + r][dg * 16 + row_g]) = c + oacc[mi][dg];
                }
                if (G == 0) comb[mi * 16 + r][64] += oL[mi][0];
            }
        }
        __syncthreads();
        if (wave == 3) {
            #pragma unroll
            for (int mi = 0; mi < 4; ++mi) {
                float l = comb[mi * 16 + r][64] + oL[mi][0];
                float il = 1.0f / l;
                size_t tok = (size_t)(b * SEQ + qbw + mi * 16 + r);
                #pragma unroll
                for (int dg = 0; dg < 4; ++dg) {
                    f32x4 tot = *reinterpret_cast<f32x4*>(&comb[mi * 16 + r][dg * 16 + row_g]);
                    tot = tot + oacc[mi][dg];
                    ushort4 o;
                    o.x = f2bf(tot[0] * il);
                    o.y = f2bf(tot[1] * il);
                    o.z = f2bf(tot[2] * il);
                    o.w = f2bf(tot[3] * il);
                    *reinterpret_cast<ushort4*>(&av[tok * HID + h * DHEAD + dg * 16 + row_g]) = o;
                }
            }
        }
        __syncthreads();   // comb safe for next job's overwrite
    }
}

extern "C" void kernel_launch(void* const* d_in, const int* in_sizes, int n_in,
                              void* d_out, int out_size, void* d_ws, size_t ws_size,
                              hipStream_t stream) {
    const float* x     = (const float*)d_in[0];
    const float* W_qkv = (const float*)d_in[1];
    const float* b_qkv = (const float*)d_in[2];
    const float* W_o   = (const float*)d_in[3];
    const float* b_o   = (const float*)d_in[4];
    float* out = (float*)d_out;

    const int n_x    = NTOK * HID;
    const int n_wqkv = QKV_N * HID;
    const int n_wo   = HID * HID;
    const int n_qkv  = NTOK * QKV_N;
    const int n_av   = NTOK * HID;

    short* xb    = (short*)d_ws;
    short* wqkvb = xb + n_x;
    short* wob   = wqkvb + n_wqkv;
    short* qkv   = wob + n_wo;
    short* av    = qkv + n_qkv;
    short* vP    = av + n_av;

    cast_f32_bf16<<<n_x / 1024,    256, 0, stream>>>(x,     (unsigned short*)xb,    n_x / 4);
    cast_f32_bf16<<<n_wqkv / 1024, 256, 0, stream>>>(W_qkv, (unsigned short*)wqkvb, n_wqkv / 4);
    cast_f32_bf16<<<n_wo / 1024,   256, 0, stream>>>(W_o,   (unsigned short*)wob,   n_wo / 4);

    // qkv = x @ W_qkv^T + b_qkv  -> bf16 [4096][3072], Q columns pre-scaled by QSCL
    gemm_bt<128, 2><<<(NTOK / 128) * (QKV_N / 128), 256, 0, stream>>>(
        xb, wqkvb, b_qkv, (void*)qkv, NTOK, QKV_N, HID);

    // vP [32 bh][64 T][64 d][32 j] (PV-fragment order)
    transpose_v<<<dim3(SEQ / 64, BATCH * NHEAD), 256, 0, stream>>>(qkv, vP);

    // attention -> av bf16 [4096][1024]; 512 uniform pair-blocks x 4 waves
    attn_fwd<<<512, 256, 0, stream>>>(qkv, vP, av);

    // out = av @ W_o^T + b_o  -> fp32
    gemm_bt<64, 0><<<(NTOK / 128) * (HID / 64), 256, 0, stream>>>(
        av, wob, b_o, (void*)out, NTOK, HID, HID);
}

// Round 17
// 113.628 us; speedup vs baseline: 1.1168x; 1.0085x over previous
//
#include <hip/hip_runtime.h>
#include <cstdint>
#include <cstddef>

// ---------- constants for this problem ----------
#define BATCH 2
#define SEQ   2048
#define HID   1024
#define NHEAD 16
#define DHEAD 64
#define QKV_N 3072   // 3*HID
#define NTOK  4096   // BATCH*SEQ

typedef __attribute__((ext_vector_type(4))) float f32x4;
typedef __attribute__((ext_vector_type(8))) short bf16x8;

#define QSCL 0.18033688011112042f   // (1/8) * log2(e), folded into Q at GEMM epilogue

__device__ inline unsigned short f2bf(float f) {
    union { float f; unsigned int u; } v; v.f = f;
    unsigned int u = v.u;
    unsigned int r = (u + 0x7fffu + ((u >> 16) & 1u)) >> 16;
    return (unsigned short)r;
}

// pack two positive floats to bf16 pair (round-half-up): P in [0,1], no NaN/inf.
__device__ __forceinline__ unsigned int pack_bf16_rh(float a, float b) {
    union { float f; unsigned int u; } ua, ub;
    ua.f = a; ub.f = b;
    return ((ua.u + 0x8000u) >> 16) | ((ub.u + 0x8000u) & 0xffff0000u);
}

__device__ __forceinline__ void gload_lds16(const void* g, void* l) {
    __builtin_amdgcn_global_load_lds(
        (const __attribute__((address_space(1))) void*)g,
        (__attribute__((address_space(3))) void*)l, 16, 0, 0);
}

// ---------- cast fp32 -> bf16 (packed ushort4) ----------
__global__ void cast_f32_bf16(const float* __restrict__ in, unsigned short* __restrict__ out, int n4) {
    int i = blockIdx.x * blockDim.x + threadIdx.x;
    if (i >= n4) return;
    float4 v = reinterpret_cast<const float4*>(in)[i];
    ushort4 o;
    o.x = f2bf(v.x); o.y = f2bf(v.y); o.z = f2bf(v.z); o.w = f2bf(v.w);
    reinterpret_cast<ushort4*>(out)[i] = o;
}

// ---------- GEMM, 2-phase dbuf pipeline, BK=32 (R5/R13 verified) ----------
template<int BN, int OUT_MODE>
__global__ __launch_bounds__(256) void gemm_bt(const short* __restrict__ A,
                                               const short* __restrict__ B,
                                               const float* __restrict__ bias,
                                               void* __restrict__ Cout,
                                               int M, int N, int K) {
    constexpr int WTN = BN / 2;
    constexpr int NJ  = WTN / 16;
    constexpr int NBC = BN / 64;

    __shared__ short sA[2][128 * 32];
    __shared__ short sB[2][BN * 32];

    const int tid  = threadIdx.x;
    const int lane = tid & 63;
    const int wave = tid >> 6;
    const int wm = wave >> 1, wn = wave & 1;

    const int nwg = gridDim.x;
    const int swz = (blockIdx.x & 7) * (nwg >> 3) + (blockIdx.x >> 3);
    const int tiles_n = N / BN;
    const int m0 = (swz / tiles_n) * 128;
    const int n0 = (swz % tiles_n) * BN;

    f32x4 acc[4][NJ];
    #pragma unroll
    for (int i = 0; i < 4; ++i)
        #pragma unroll
        for (int j = 0; j < NJ; ++j) acc[i][j] = (f32x4){0.f, 0.f, 0.f, 0.f};

    const int r = lane & 15;
    const int G = lane >> 4;

    #define GSTAGE(kt_, buf_)                                                          \
        {                                                                              \
            _Pragma("unroll")                                                          \
            for (int i = 0; i < 2; ++i) {                                              \
                int ga = (i * 4 + wave) * 64 + lane;                                   \
                int row = ga >> 2, gcol = (ga & 3) ^ (row & 3);                        \
                gload_lds16(A + (size_t)(m0 + row) * K + (kt_) + gcol * 8,             \
                            &sA[buf_][(i * 4 + wave) * 512]);                          \
            }                                                                          \
            _Pragma("unroll")                                                          \
            for (int i = 0; i < NBC; ++i) {                                            \
                int gb = (i * 4 + wave) * 64 + lane;                                   \
                int row = gb >> 2, gcol = (gb & 3) ^ (row & 3);                        \
                gload_lds16(B + (size_t)(n0 + row) * K + (kt_) + gcol * 8,             \
                            &sB[buf_][(i * 4 + wave) * 512]);                          \
            }                                                                          \
        }

    GSTAGE(0, 0);
    __syncthreads();
    int cur = 0;

    const int nsteps = K >> 5;
    for (int ks = 0; ks < nsteps; ++ks) {
        if (ks + 1 < nsteps) GSTAGE((ks + 1) * 32, cur ^ 1);

        const int sg = G ^ (r & 3);
        bf16x8 af[4], bfr[NJ];
        #pragma unroll
        for (int i = 0; i < 4; ++i) {
            int row = wm * 64 + i * 16 + r;
            af[i] = *reinterpret_cast<const bf16x8*>(&sA[cur][row * 32 + sg * 8]);
        }
        #pragma unroll
        for (int j = 0; j < NJ; ++j) {
            int row = wn * WTN + j * 16 + r;
            bfr[j] = *reinterpret_cast<const bf16x8*>(&sB[cur][row * 32 + sg * 8]);
        }
        #pragma unroll
        for (int i = 0; i < 4; ++i)
            #pragma unroll
            for (int j = 0; j < NJ; ++j)
                acc[i][j] = __builtin_amdgcn_mfma_f32_16x16x32_bf16(af[i], bfr[j], acc[i][j], 0, 0, 0);

        __syncthreads();
        cur ^= 1;
    }
    #undef GSTAGE

    const int col_l = lane & 15;
    const int row_g = (lane >> 4) * 4;
    #pragma unroll
    for (int i = 0; i < 4; ++i) {
        #pragma unroll
        for (int j = 0; j < NJ; ++j) {
            int nn = n0 + wn * WTN + j * 16 + col_l;
            float bv = bias[nn];
            float scl = (OUT_MODE == 2 && nn < HID) ? QSCL : 1.0f;
            #pragma unroll
            for (int reg = 0; reg < 4; ++reg) {
                int mm = m0 + wm * 64 + i * 16 + row_g + reg;
                float v = (acc[i][j][reg] + bv) * scl;
                if (OUT_MODE == 0) {
                    reinterpret_cast<float*>(Cout)[(size_t)mm * N + nn] = v;
                } else {
                    reinterpret_cast<unsigned short*>(Cout)[(size_t)mm * N + nn] = f2bf(v);
                }
            }
        }
    }
}

// ---------- transpose V part of qkv -> vP [bh][T][d][j] (PV-fragment order) ----------
// (unchanged from R11 -- verified)
#define TLDP 72
__global__ __launch_bounds__(256) void transpose_v(const short* __restrict__ qkv,
                                                   short* __restrict__ vP) {
    const int st = blockIdx.x;
    const int bh = blockIdx.y;
    const int b  = bh >> 4, h = bh & 15;
    __shared__ short ld[64 * TLDP];
    const int tid = threadIdx.x;

    #pragma unroll
    for (int i = 0; i < 2; ++i) {
        int idx = i * 256 + tid;
        int row = idx >> 3, c = idx & 7;
        int4 v = *reinterpret_cast<const int4*>(
            qkv + ((size_t)(b * SEQ + st * 64 + row)) * QKV_N + 2 * HID + h * DHEAD + c * 8);
        *reinterpret_cast<int4*>(&ld[row * TLDP + c * 8]) = v;
    }
    __syncthreads();
    #pragma unroll
    for (int i = 0; i < 2; ++i) {
        int u  = i * 256 + tid;
        int Tp = u >> 8;
        int d  = (u >> 2) & 63;
        int p  = u & 3;
        int b0 = Tp * 32 + 4 * p;
        int b1 = b0 + 16;
        ushort4 o0, o1;
        o0.x = (unsigned short)ld[(b0 + 0) * TLDP + d];
        o0.y = (unsigned short)ld[(b0 + 1) * TLDP + d];
        o0.z = (unsigned short)ld[(b0 + 2) * TLDP + d];
        o0.w = (unsigned short)ld[(b0 + 3) * TLDP + d];
        o1.x = (unsigned short)ld[(b1 + 0) * TLDP + d];
        o1.y = (unsigned short)ld[(b1 + 1) * TLDP + d];
        o1.z = (unsigned short)ld[(b1 + 2) * TLDP + d];
        o1.w = (unsigned short)ld[(b1 + 3) * TLDP + d];
        size_t out = ((size_t)((bh * 64 + st * 2 + Tp) * 64 + d)) * 32 + p * 8;
        *reinterpret_cast<ushort4*>(&vP[out])     = o0;
        *reinterpret_cast<ushort4*>(&vP[out + 4]) = o1;
    }
}

// ---------- flash attention (causal): pair-balanced + 64-kv iterations ----------
// R16 post-mortem: per-iteration fixed stall ~1.7K cyc dominates; compiler sank the
// register pipeline (VGPR only +8). R17: process TWO 32-kv subtiles per iteration,
// ALL 16 loads issued at iteration top -- subtile-1's load latency hides under
// subtile-0's compute (nothing to sink: data used within the iteration), and the
// fixed per-iteration cost is paid half as often. T(qb) = 2qb+2 is even -> exactly
// qb+1 pairs; blocks stay uniform via job-pairing (33 pairs/block). Verified algebra
// byte-identical (R13/R16 body).
__global__ __launch_bounds__(256, 2) void attn_fwd(const short* __restrict__ qkv,
                                                   const short* __restrict__ vP,
                                                   short* __restrict__ av) {
    const int bid = blockIdx.x;
    const int pi  = bid >> 5;            // 0..15 (pair index)
    const int bh  = bid & 31;            // bid%8 == bh%8 -> per-head XCD affinity
    const int b   = bh >> 4;
    const int h   = bh & 15;

    __shared__ float comb[64][68];       // cols 0..63 = O[q][d], col 64 = L[q]

    const int tid  = threadIdx.x;
    const int lane = tid & 63;
    const int wave = tid >> 6;           // 0..3 (kv-pair split)
    const int r    = lane & 15;
    const int G    = lane >> 4;
    const int row_g = G * 4;

    bf16x8 ones;
    #pragma unroll
    for (int e = 0; e < 8; ++e) ones[e] = (short)0x3f80;   // bf16 1.0

    // job-invariant per-lane K/V base pointers (wave's first pair = wave -> kv 64*wave)
    const short* kpt0 = qkv + (size_t)(b * SEQ + wave * 64) * QKV_N + HID + h * DHEAD
                        + r * QKV_N + G * 8;
    const short* vpt0 = vP + (size_t)(bh * 64 + wave * 2) * 2048 + r * 32 + G * 8;
    const ptrdiff_t KSTEP = (ptrdiff_t)256 * QKV_N;   // 4 pairs x 64 kv rows
    const ptrdiff_t VSTEP = 8 * 2048;                 // 4 pairs x 2 tiles
    const int KG1 = 16 * QKV_N;                       // +16 kv rows (g=1)
    const int KH  = 32 * QKV_N;                       // subtile-1 offset (+32 kv)

    // one 32-kv subtile: loads already in registers; verified R13/R16 compute body
    #define SUBTILE(K00_, K01_, K10_, K11_, V0_, V1_, V2_, V3_, TG_)                       \
        {                                                                                  \
            bf16x8 kb[2][2], vb[4];                                                        \
            __builtin_memcpy(&kb[0][0], &K00_, 16);                                        \
            __builtin_memcpy(&kb[0][1], &K01_, 16);                                        \
            __builtin_memcpy(&kb[1][0], &K10_, 16);                                        \
            __builtin_memcpy(&kb[1][1], &K11_, 16);                                        \
            __builtin_memcpy(&vb[0], &V0_, 16);                                            \
            __builtin_memcpy(&vb[1], &V1_, 16);                                            \
            __builtin_memcpy(&vb[2], &V2_, 16);                                            \
            __builtin_memcpy(&vb[3], &V3_, 16);                                            \
            _Pragma("unroll")                                                              \
            for (int mi = 0; mi < 4; ++mi) {                                               \
                f32x4 s[2];                                                                \
                __builtin_amdgcn_s_setprio(1);                                             \
                _Pragma("unroll")                                                          \
                for (int g = 0; g < 2; ++g) {                                              \
                    f32x4 z = (f32x4){0.f, 0.f, 0.f, 0.f};                                 \
                    z = __builtin_amdgcn_mfma_f32_16x16x32_bf16(kb[g][0], qf[mi][0], z, 0, 0, 0); \
                    z = __builtin_amdgcn_mfma_f32_16x16x32_bf16(kb[g][1], qf[mi][1], z, 0, 0, 0); \
                    s[g] = z;                                                              \
                }                                                                          \
                __builtin_amdgcn_s_setprio(0);                                             \
                if (band) {                                                                \
                    int qg = qbw + mi * 16 + r;                                            \
                    _Pragma("unroll")                                                      \
                    for (int g = 0; g < 2; ++g) {                                          \
                        _Pragma("unroll")                                                  \
                        for (int reg = 0; reg < 4; ++reg) {                                \
                            int kvg = (TG_) * 32 + g * 16 + row_g + reg;                   \
                            if (kvg > qg) s[g][reg] = -30000.f;                            \
                        }                                                                  \
                    }                                                                      \
                }                                                                          \
                float p0 = __builtin_amdgcn_exp2f(s[0][0]);                                \
                float p1 = __builtin_amdgcn_exp2f(s[0][1]);                                \
                float p2 = __builtin_amdgcn_exp2f(s[0][2]);                                \
                float p3 = __builtin_amdgcn_exp2f(s[0][3]);                                \
                float p4 = __builtin_amdgcn_exp2f(s[1][0]);                                \
                float p5 = __builtin_amdgcn_exp2f(s[1][1]);                                \
                float p6 = __builtin_amdgcn_exp2f(s[1][2]);                                \
                float p7 = __builtin_amdgcn_exp2f(s[1][3]);                                \
                unsigned int w0 = pack_bf16_rh(p0, p1);                                    \
                unsigned int w1 = pack_bf16_rh(p2, p3);                                    \
                unsigned int w2 = pack_bf16_rh(p4, p5);                                    \
                unsigned int w3 = pack_bf16_rh(p6, p7);                                    \
                bf16x8 pb;                                                                 \
                { int4 f; f.x = (int)w0; f.y = (int)w1; f.z = (int)w2; f.w = (int)w3;      \
                  __builtin_memcpy(&pb, &f, 16); }                                         \
                __builtin_amdgcn_s_setprio(1);                                             \
                _Pragma("unroll")                                                          \
                for (int dg = 0; dg < 4; ++dg)                                             \
                    oacc[mi][dg] = __builtin_amdgcn_mfma_f32_16x16x32_bf16(vb[dg], pb, oacc[mi][dg], 0, 0, 0); \
                oL[mi] = __builtin_amdgcn_mfma_f32_16x16x32_bf16(ones, pb, oL[mi], 0, 0, 0); \
                __builtin_amdgcn_s_setprio(0);                                             \
            }                                                                              \
        }

    #pragma unroll 1
    for (int job = 0; job < 2; ++job) {
        const int qb  = job == 0 ? 31 - pi : pi;   // heavy job first
        const int qbw = qb * 64;

        // Q fragments for 4 mi (pre-scaled by QSCL); B-frag: col = q = r, k = d
        bf16x8 qf[4][2];
        #pragma unroll
        for (int mi = 0; mi < 4; ++mi) {
            const short* Qg = qkv + ((size_t)(b * SEQ + qbw + mi * 16 + r)) * QKV_N + h * DHEAD;
            qf[mi][0] = *reinterpret_cast<const bf16x8*>(Qg + G * 8);
            qf[mi][1] = *reinterpret_cast<const bf16x8*>(Qg + 32 + G * 8);
        }

        f32x4 oacc[4][4];
        f32x4 oL[4];
        #pragma unroll
        for (int mi = 0; mi < 4; ++mi) {
            oL[mi] = (f32x4){0.f, 0.f, 0.f, 0.f};
            #pragma unroll
            for (int dg = 0; dg < 4; ++dg) oacc[mi][dg] = (f32x4){0.f, 0.f, 0.f, 0.f};
        }

        const short* kpt = kpt0;
        const short* vpt = vpt0;

        // pairs 0..qb; wave takes {wave, wave+4, ...}
        for (int tp = wave; tp <= qb; tp += 4) {
            // issue ALL 16 loads up front (subtile-1 latency hides under subtile-0 compute)
            int4 ka00 = *reinterpret_cast<const int4*>(kpt);
            int4 ka01 = *reinterpret_cast<const int4*>(kpt + 32);
            int4 ka10 = *reinterpret_cast<const int4*>(kpt + KG1);
            int4 ka11 = *reinterpret_cast<const int4*>(kpt + KG1 + 32);
            int4 kb00 = *reinterpret_cast<const int4*>(kpt + KH);
            int4 kb01 = *reinterpret_cast<const int4*>(kpt + KH + 32);
            int4 kb10 = *reinterpret_cast<const int4*>(kpt + KH + KG1);
            int4 kb11 = *reinterpret_cast<const int4*>(kpt + KH + KG1 + 32);
            int4 va0 = *reinterpret_cast<const int4*>(vpt);
            int4 va1 = *reinterpret_cast<const int4*>(vpt + 16 * 32);
            int4 va2 = *reinterpret_cast<const int4*>(vpt + 32 * 32);
            int4 va3 = *reinterpret_cast<const int4*>(vpt + 48 * 32);
            int4 vb0 = *reinterpret_cast<const int4*>(vpt + 2048);
            int4 vb1 = *reinterpret_cast<const int4*>(vpt + 2048 + 16 * 32);
            int4 vb2 = *reinterpret_cast<const int4*>(vpt + 2048 + 32 * 32);
            int4 vb3 = *reinterpret_cast<const int4*>(vpt + 2048 + 48 * 32);
            kpt += KSTEP;
            vpt += VSTEP;

            const bool band = (tp == qb);   // only the last pair crosses the diagonal

            SUBTILE(ka00, ka01, ka10, ka11, va0, va1, va2, va3, 2 * tp);
            SUBTILE(kb00, kb01, kb10, kb11, vb0, vb1, vb2, vb3, 2 * tp + 1);
        }

        // ---- combine (pure sums over kv): 3-barrier serial LDS add (verified) ----
        __syncthreads();
        if (wave == 0) {
            #pragma unroll
            for (int mi = 0; mi < 4; ++mi) {
                #pragma unroll
                for (int dg = 0; dg < 4; ++dg)
                    *reinterpret_cast<f32x4*>(&comb[mi * 16 + r][dg * 16 + row_g]) = oacc[mi][dg];
                if (G == 0) comb[mi * 16 + r][64] = oL[mi][0];
            }
        }
        __syncthreads();
        if (wave == 1) {
            #pragma unroll
            for (int mi = 0; mi < 4; ++mi) {
                #pragma unroll
                for (int dg = 0; dg < 4; ++dg) {
                    f32x4 c = *reinterpret_cast<f32x4*>(&comb[mi * 16 + r][dg * 16 + row_g]);
                    *reinterpret_cast<f32x4*>(&comb[mi * 16 + r][dg * 16 + row_g]) = c + oacc[mi][dg];
                }
                if (G == 0) comb[mi * 16 + r][64] += oL[mi][0];
            }
        }
        __syncthreads();
        if (wave == 2) {
            #pragma unroll
            for (int mi = 0; mi < 4; ++mi) {
                #pragma unroll
                for (int dg = 0; dg < 4; ++dg) {
                    f32x4 c = *reinterpret_cast<f32x4*>(&comb[mi * 16 + r][dg * 16 + row_g]);
                    *reinterpret_cast<f32x4*>(&comb[mi * 16 + r][dg * 16 + row_g]) = c + oacc[mi][dg];
                }
                if (G == 0) comb[mi * 16 + r][64] += oL[mi][0];
            }
        }
        __syncthreads();
        if (wave == 3) {
            #pragma unroll
            for (int mi = 0; mi < 4; ++mi) {
                float l = comb[mi * 16 + r][64] + oL[mi][0];
                float il = 1.0f / l;
                size_t tok = (size_t)(b * SEQ + qbw + mi * 16 + r);
                #pragma unroll
                for (int dg = 0; dg < 4; ++dg) {
                    f32x4 tot = *reinterpret_cast<f32x4*>(&comb[mi * 16 + r][dg * 16 + row_g]);
                    tot = tot + oacc[mi][dg];
                    ushort4 o;
                    o.x = f2bf(tot[0] * il);
                    o.y = f2bf(tot[1] * il);
                    o.z = f2bf(tot[2] * il);
                    o.w = f2bf(tot[3] * il);
                    *reinterpret_cast<ushort4*>(&av[tok * HID + h * DHEAD + dg * 16 + row_g]) = o;
                }
            }
        }
        __syncthreads();   // comb safe for next job's overwrite
    }
    #undef SUBTILE
}

extern "C" void kernel_launch(void* const* d_in, const int* in_sizes, int n_in,
                              void* d_out, int out_size, void* d_ws, size_t ws_size,
                              hipStream_t stream) {
    const float* x     = (const float*)d_in[0];
    const float* W_qkv = (const float*)d_in[1];
    const float* b_qkv = (const float*)d_in[2];
    const float* W_o   = (const float*)d_in[3];
    const float* b_o   = (const float*)d_in[4];
    float* out = (float*)d_out;

    const int n_x    = NTOK * HID;
    const int n_wqkv = QKV_N * HID;
    const int n_wo   = HID * HID;
    const int n_qkv  = NTOK * QKV_N;
    const int n_av   = NTOK * HID;

    short* xb    = (short*)d_ws;
    short* wqkvb = xb + n_x;
    short* wob   = wqkvb + n_wqkv;
    short* qkv   = wob + n_wo;
    short* av    = qkv + n_qkv;
    short* vP    = av + n_av;

    cast_f32_bf16<<<n_x / 1024,    256, 0, stream>>>(x,     (unsigned short*)xb,    n_x / 4);
    cast_f32_bf16<<<n_wqkv / 1024, 256, 0, stream>>>(W_qkv, (unsigned short*)wqkvb, n_wqkv / 4);
    cast_f32_bf16<<<n_wo / 1024,   256, 0, stream>>>(W_o,   (unsigned short*)wob,   n_wo / 4);

    // qkv = x @ W_qkv^T + b_qkv  -> bf16 [4096][3072], Q columns pre-scaled by QSCL
    gemm_bt<128, 2><<<(NTOK / 128) * (QKV_N / 128), 256, 0, stream>>>(
        xb, wqkvb, b_qkv, (void*)qkv, NTOK, QKV_N, HID);

    // vP [32 bh][64 T][64 d][32 j] (PV-fragment order)
    transpose_v<<<dim3(SEQ / 64, BATCH * NHEAD), 256, 0, stream>>>(qkv, vP);

    // attention -> av bf16 [4096][1024]; 512 uniform pair-blocks x 4 waves, 64-kv iters
    attn_fwd<<<512, 256, 0, stream>>>(qkv, vP, av);

    // out = av @ W_o^T + b_o  -> fp32
    gemm_bt<64, 0><<<(NTOK / 128) * (HID / 64), 256, 0, stream>>>(
        av, wob, b_o, (void*)out, NTOK, HID, HID);
}